// Round 10
// baseline (77.433 us; speedup 1.0000x reference)
//
#include <hip/hip_runtime.h>
#include <math.h>

// VectorExpansionCalculator. Output f32 blocks: [E,1,8]|[E,3,7]|[E,5,6]|[E,7,5].
// R1 scattered: 137us. R2 LDS staging: 79. R4 (+native sin, nt, staged s0):
// 74.9. R5 XCD swizzle: refuted. R6 persistent chunked: refuted (imbalance).
// R7 per-section kernels: null. R8 fused section-partition: 73.2 (best).
// R9 plain stores: 76.9 -> nt stores proven +5%, kept.
// R10 (this): persistent 4-task blocks per section (977 blocks x 4 contiguous
// tasks, near-perfect balance) + cross-task v-prefetch — tests the last
// untried mechanism: unhidden per-task dependency-chain latency.

#define RCUT 5.0f
#define EPSF 1e-12f

typedef float fx4 __attribute__((ext_vector_type(4)));

__device__ __forceinline__ void radial(float rr, float ir, float rb[8]) {
  float theta = (3.14159265358979323846f / RCUT) * rr;
  float s = __sinf(theta);
  float c = __cosf(theta);
  float fcut = (rr < RCUT) ? 0.5f * (c + 1.0f) : 0.0f;
  float g = fcut * ir;
  float twoc = 2.0f * c;
  float sp = 0.0f, sn = s;
  rb[0] = sn * g;
#pragma unroll
  for (int n = 1; n < 8; ++n) {
    float s2 = twoc * sn - sp;
    sp = sn;
    sn = s2;
    rb[n] = sn * g;
  }
}

// Compute + LDS-stage + nt-flush one 64-edge wave-task from preloaded v.
template <int L>
__device__ __forceinline__ void emit_task(float x, float y, float z,
                                          long long e0, int E,
                                          float* __restrict__ secbase,
                                          fx4* __restrict__ l4, int lane) {
  constexpr int M = 2 * L + 1;
  constexpr int NM = 8 - L;
  constexpr int S = M * NM;
  const bool fullwave = (e0 + 64 <= (long long)E);
  const int e = (int)e0 + lane;
  const bool valid = e < E;

  float rr = sqrtf(x * x + y * y + z * z);
  float ir = 1.0f / (rr + EPSF);
  float rb[8];
  radial(rr, ir, rb);

  float ux = x * ir, uy = y * ir, uz = z * ir;
  float xx = ux * ux, yy = uy * uy, zz = uz * uz;

  float sh[M];
  if constexpr (L == 1) {
    const float c1 = 0.48860251190291992f;
    sh[0] = c1 * uy;
    sh[1] = c1 * uz;
    sh[2] = c1 * ux;
  } else if constexpr (L == 2) {
    const float c2a = 1.09254843059207907f;
    const float c2b = 0.31539156525252001f;
    const float c2c = 0.54627421529603953f;
    sh[0] = c2a * ux * uy;
    sh[1] = c2a * uy * uz;
    sh[2] = c2b * (2.0f * zz - xx - yy);
    sh[3] = c2a * ux * uz;
    sh[4] = c2c * (xx - yy);
  } else {
    const float c3a = 0.59004358992664352f;
    const float c3b = 2.89061144264055405f;
    const float c3c = 0.45704579946446574f;
    const float c3d = 0.37317633259011546f;
    const float c3e = 1.44530572132027702f;
    sh[0] = c3a * uy * (3.0f * xx - yy);
    sh[1] = c3b * ux * uy * uz;
    sh[2] = c3c * uy * (4.0f * zz - xx - yy);
    sh[3] = c3d * uz * (2.0f * zz - 3.0f * xx - 3.0f * yy);
    sh[4] = c3c * ux * (4.0f * zz - xx - yy);
    sh[5] = c3e * uz * (xx - yy);
    sh[6] = c3a * ux * (xx - 3.0f * yy);
  }

  float vals[S];
#pragma unroll
  for (int m = 0; m < M; ++m)
#pragma unroll
    for (int n = 0; n < NM; ++n) vals[m * NM + n] = sh[m] * rb[n];

  if (fullwave) {
    float* lw = reinterpret_cast<float*>(l4);
#pragma unroll
    for (int i = 0; i < S; ++i) lw[lane * S + i] = vals[i];
    fx4* g4 = reinterpret_cast<fx4*>(secbase + (size_t)e0 * S);
    constexpr int NF4 = 16 * S;
    constexpr int NITER = (NF4 + 63) / 64;
#pragma unroll
    for (int it = 0; it < NITER; ++it) {
      int k = lane + it * 64;
      if ((NF4 % 64 == 0) || k < NF4)
        __builtin_nontemporal_store(l4[k], &g4[k]);
    }
  } else if (valid) {
    float* o = secbase + (size_t)e * S;
#pragma unroll
    for (int i = 0; i < S; ++i) o[i] = vals[i];
  }
}

// 4 contiguous 256-edge tasks per block; prefetch next task's v before the
// current task's LDS/flush phase so load latency hides under the store phase.
template <int L>
__device__ __forceinline__ void do_sec_pipe(const float* __restrict__ v,
                                            float* __restrict__ secbase, int E,
                                            int t0, int ntask,
                                            fx4* __restrict__ l4, int lane,
                                            int wave) {
  float cx = 0.0f, cy = 0.0f, cz = 0.0f;
  {
    long long e0 = ((long long)t0 * 4 + wave) * 64;
    int e = (int)e0 + lane;
    if (e0 < E && e < E) {
      cx = v[3 * (size_t)e + 0];
      cy = v[3 * (size_t)e + 1];
      cz = v[3 * (size_t)e + 2];
    }
  }
#pragma unroll
  for (int j = 0; j < 4; ++j) {
    int task = t0 + j;
    long long e0 = ((long long)task * 4 + wave) * 64;
    float nx = 0.0f, ny = 0.0f, nz = 0.0f;
    if (j < 3) {  // prefetch next task's v (independent of this task's work)
      long long en0 = ((long long)(task + 1) * 4 + wave) * 64;
      int en = (int)en0 + lane;
      if (en0 < E && en < E) {
        nx = v[3 * (size_t)en + 0];
        ny = v[3 * (size_t)en + 1];
        nz = v[3 * (size_t)en + 2];
      }
    }
    if (task < ntask && e0 < E)
      emit_task<L>(cx, cy, cz, e0, E, secbase, l4, lane);
    cx = nx;
    cy = ny;
    cz = nz;
  }
}

__global__ __launch_bounds__(256) void vexp_fused(const float* __restrict__ v,
                                                  float* __restrict__ out,
                                                  int E, int nb, int ntask,
                                                  int iters0) {
  __shared__ fx4 lbuf[4][560];  // 35.8 KB -> 4 blocks/CU
  const int bid = blockIdx.x;
  const int lane = threadIdx.x & 63;
  const int wave = threadIdx.x >> 6;
  const size_t E_ = (size_t)E;

  if (bid < nb) {
    // ---- section 0: [E,1,8]. Thread-per-fx4, strided persistent loop.
    const long long n4 = 2LL * E;
    const long long stride = (long long)nb * 256;
    long long t = (long long)bid * 256 + threadIdx.x;
    const float y0c = 0.28209479177387814f;
#pragma unroll 2
    for (int it = 0; it < iters0; ++it) {
      if (t < n4) {
        long long e = t >> 1;
        int half = (int)(t & 1);
        float x = v[3 * e + 0], y = v[3 * e + 1], z = v[3 * e + 2];
        float rr = sqrtf(x * x + y * y + z * z);
        float ir = 1.0f / (rr + EPSF);
        float rb[8];
        radial(rr, ir, rb);
        int o = 4 * half;
        fx4 val = {y0c * rb[o], y0c * rb[o + 1], y0c * rb[o + 2],
                   y0c * rb[o + 3]};
        __builtin_nontemporal_store(val, &reinterpret_cast<fx4*>(out)[t]);
      }
      t += stride;
    }
  } else if (bid < 2 * nb) {
    do_sec_pipe<1>(v, out + 8 * E_, E, (bid - nb) * 4, ntask, lbuf[wave],
                   lane, wave);
  } else if (bid < 3 * nb) {
    do_sec_pipe<2>(v, out + 29 * E_, E, (bid - 2 * nb) * 4, ntask, lbuf[wave],
                   lane, wave);
  } else {
    do_sec_pipe<3>(v, out + 59 * E_, E, (bid - 3 * nb) * 4, ntask, lbuf[wave],
                   lane, wave);
  }
}

extern "C" void kernel_launch(void* const* d_in, const int* in_sizes, int n_in,
                              void* d_out, int out_size, void* d_ws, size_t ws_size,
                              hipStream_t stream) {
  const float* v = (const float*)d_in[0];
  float* out = (float*)d_out;
  int E = in_sizes[0] / 3;
  int waves = (E + 63) / 64;
  int ntask = (waves + 3) / 4;       // 256-edge tasks per section (3907)
  int nb = (ntask + 3) / 4;          // blocks per section, 4 tasks each (977)
  long long stride = (long long)nb * 256;
  int iters0 = (int)((2LL * E + stride - 1) / stride);  // s0 fx4 iterations
  vexp_fused<<<4 * nb, 256, 0, stream>>>(v, out, E, nb, ntask, iters0);
}

// Round 11
// 73.498 us; speedup vs baseline: 1.0535x; 1.0535x over previous
//
#include <hip/hip_runtime.h>
#include <math.h>

// VectorExpansionCalculator. Output f32 blocks: [E,1,8]|[E,3,7]|[E,5,6]|[E,7,5].
// FINAL (= R8, best at 73.2us): fused single-launch, block-range partitioned
// by section; each block writes one contiguous stream; wave-private LDS
// staging -> contiguous nontemporal dwordx4 stores.
// Ledger: R1 scattered 137us -> R2 LDS staging 79 -> R4 native sin + nt +
// staged s0 74.9 -> R8 fused partition 73.2. Refuted: XCD swizzle (76.3),
// persistent chunked (78.9), per-section kernels (74.7 null), plain stores
// (76.9), cross-task prefetch (77.4). Effective 5.3 TB/s = 78% of pure-fill.

#define RCUT 5.0f
#define EPSF 1e-12f

typedef float fx4 __attribute__((ext_vector_type(4)));

__device__ __forceinline__ void radial(float rr, float ir, float rb[8]) {
  float theta = (3.14159265358979323846f / RCUT) * rr;
  float s = __sinf(theta);
  float c = __cosf(theta);
  float fcut = (rr < RCUT) ? 0.5f * (c + 1.0f) : 0.0f;
  float g = fcut * ir;
  float twoc = 2.0f * c;
  float sp = 0.0f, sn = s;
  rb[0] = sn * g;
#pragma unroll
  for (int n = 1; n < 8; ++n) {
    float s2 = twoc * sn - sp;
    sp = sn;
    sn = s2;
    rb[n] = sn * g;
  }
}

template <int L>
__device__ __forceinline__ void do_section(const float* __restrict__ v,
                                           float* __restrict__ secbase, int E,
                                           int task, fx4* __restrict__ l4,
                                           int lane, int wave) {
  constexpr int M = 2 * L + 1;  // SH count
  constexpr int NM = 8 - L;     // n_max for this l
  constexpr int S = M * NM;     // floats per edge
  const long long e0 = ((long long)task * 4 + wave) * 64;
  if (e0 >= E) return;
  const bool fullwave = (e0 + 64 <= (long long)E);
  const int e = (int)e0 + lane;
  const bool valid = e < E;

  float x = 0.0f, y = 0.0f, z = 0.0f;
  if (valid) {
    x = v[3 * (size_t)e + 0];
    y = v[3 * (size_t)e + 1];
    z = v[3 * (size_t)e + 2];
  }
  float rr = sqrtf(x * x + y * y + z * z);
  float ir = 1.0f / (rr + EPSF);
  float rb[8];
  radial(rr, ir, rb);

  float ux = x * ir, uy = y * ir, uz = z * ir;
  float xx = ux * ux, yy = uy * uy, zz = uz * uz;

  float sh[M];
  if constexpr (L == 1) {
    const float c1 = 0.48860251190291992f;
    sh[0] = c1 * uy;
    sh[1] = c1 * uz;
    sh[2] = c1 * ux;
  } else if constexpr (L == 2) {
    const float c2a = 1.09254843059207907f;
    const float c2b = 0.31539156525252001f;
    const float c2c = 0.54627421529603953f;
    sh[0] = c2a * ux * uy;
    sh[1] = c2a * uy * uz;
    sh[2] = c2b * (2.0f * zz - xx - yy);
    sh[3] = c2a * ux * uz;
    sh[4] = c2c * (xx - yy);
  } else {
    const float c3a = 0.59004358992664352f;
    const float c3b = 2.89061144264055405f;
    const float c3c = 0.45704579946446574f;
    const float c3d = 0.37317633259011546f;
    const float c3e = 1.44530572132027702f;
    sh[0] = c3a * uy * (3.0f * xx - yy);
    sh[1] = c3b * ux * uy * uz;
    sh[2] = c3c * uy * (4.0f * zz - xx - yy);
    sh[3] = c3d * uz * (2.0f * zz - 3.0f * xx - 3.0f * yy);
    sh[4] = c3c * ux * (4.0f * zz - xx - yy);
    sh[5] = c3e * uz * (xx - yy);
    sh[6] = c3a * ux * (xx - 3.0f * yy);
  }

  float vals[S];
#pragma unroll
  for (int m = 0; m < M; ++m)
#pragma unroll
    for (int n = 0; n < NM; ++n) vals[m * NM + n] = sh[m] * rb[n];

  if (fullwave) {
    float* lw = reinterpret_cast<float*>(l4);
#pragma unroll
    for (int i = 0; i < S; ++i) lw[lane * S + i] = vals[i];
    fx4* g4 = reinterpret_cast<fx4*>(secbase + (size_t)e0 * S);
    constexpr int NF4 = 16 * S;
    constexpr int NITER = (NF4 + 63) / 64;
#pragma unroll
    for (int it = 0; it < NITER; ++it) {
      int k = lane + it * 64;
      if ((NF4 % 64 == 0) || k < NF4)
        __builtin_nontemporal_store(l4[k], &g4[k]);
    }
  } else if (valid) {
    float* o = secbase + (size_t)e * S;
#pragma unroll
    for (int i = 0; i < S; ++i) o[i] = vals[i];
  }
}

__global__ __launch_bounds__(256) void vexp_fused(const float* __restrict__ v,
                                                  float* __restrict__ out,
                                                  int E, int gsec) {
  __shared__ fx4 lbuf[4][560];  // 35.8 KB -> 4 blocks/CU
  const int bid = blockIdx.x;
  const int lane = threadIdx.x & 63;
  const int wave = threadIdx.x >> 6;
  const size_t E_ = (size_t)E;

  if (bid < gsec) {
    // ---- section 0: [E,1,8]. Thread-per-fx4, 2 grid-stride iters, no LDS.
    const long long n4 = 2LL * E;
    const float y0c = 0.28209479177387814f;
#pragma unroll
    for (int k = 0; k < 2; ++k) {
      long long t = (long long)bid * 256 + threadIdx.x + (long long)k * gsec * 256;
      if (t < n4) {
        long long e = t >> 1;
        int half = (int)(t & 1);
        float x = v[3 * e + 0], y = v[3 * e + 1], z = v[3 * e + 2];
        float rr = sqrtf(x * x + y * y + z * z);
        float ir = 1.0f / (rr + EPSF);
        float rb[8];
        radial(rr, ir, rb);
        int o = 4 * half;
        fx4 val = {y0c * rb[o], y0c * rb[o + 1], y0c * rb[o + 2],
                   y0c * rb[o + 3]};
        __builtin_nontemporal_store(val, &reinterpret_cast<fx4*>(out)[t]);
      }
    }
  } else if (bid < 2 * gsec) {
    do_section<1>(v, out + 8 * E_, E, bid - gsec, lbuf[wave], lane, wave);
  } else if (bid < 3 * gsec) {
    do_section<2>(v, out + 29 * E_, E, bid - 2 * gsec, lbuf[wave], lane, wave);
  } else {
    do_section<3>(v, out + 59 * E_, E, bid - 3 * gsec, lbuf[wave], lane, wave);
  }
}

extern "C" void kernel_launch(void* const* d_in, const int* in_sizes, int n_in,
                              void* d_out, int out_size, void* d_ws, size_t ws_size,
                              hipStream_t stream) {
  const float* v = (const float*)d_in[0];
  float* out = (float*)d_out;
  int E = in_sizes[0] / 3;
  int waves = (E + 63) / 64;
  int gsec = (waves + 3) / 4;  // 256-edge tasks per section
  vexp_fused<<<4 * gsec, 256, 0, stream>>>(v, out, E, gsec);
}